// Round 10
// baseline (1330.940 us; speedup 1.0000x reference)
//
#include <hip/hip_runtime.h>

#define N_NODES 100000
#define N_EDGES 1600000
#define HID 100
#define NG 128
#define NC 8
#define NSCAN 391  // ceil(N_NODES / 256)
#define XCD 8
#define SLICE_NODES 12500  // N_NODES / XCD
#define PUSH_BLOCKS 512

// Degree count (in-deg AND out-deg), XCD-sliced: blocks with same blockIdx&7
// land on one XCD (perf heuristic); each slice-group streams src+dst coalesced
// and only atomics its own 12.5K-node window -> L2-local RMW.
static __global__ void degb_k(const int* __restrict__ ei, int* __restrict__ degi,
                              int* __restrict__ degs) {
  int slice = blockIdx.x & (XCD - 1);
  int lo = slice * SLICE_NODES;
  int hi = min(lo + SLICE_NODES, N_NODES);
  int bid = blockIdx.x >> 3;
  int stride = (gridDim.x >> 3) * blockDim.x;
  for (int e = bid * blockDim.x + threadIdx.x; e < N_EDGES; e += stride) {
    int s = ei[e];
    int d = ei[N_EDGES + e];
    if (d >= lo && d < hi) atomicAdd(&degi[d], 1);
    if (s >= lo && s < hi) atomicAdd(&degs[s], 1);
  }
}

// dinv (deg includes self-loop: 1+indeg) + xs = x*dinv.
static __global__ void dinv_k(const int* __restrict__ degi, const float* __restrict__ x,
                              float* __restrict__ dinv, float* __restrict__ xs) {
  int i = blockIdx.x * blockDim.x + threadIdx.x;
  if (i < N_NODES) {
    float d = 1.0f / sqrtf(1.0f + (float)degi[i]);
    dinv[i] = d;
    xs[i] = x[i] * d;
  }
}

// --- 3-phase parallel exclusive scan, two arrays via blockIdx.y (0:degi,1:degs) ---
static __global__ void reduce_k(const int* __restrict__ degi, const int* __restrict__ degs,
                                int* __restrict__ bsum) {
  const int* a = blockIdx.y ? degs : degi;
  int i = blockIdx.x * 256 + threadIdx.x;
  int v = (i < N_NODES) ? a[i] : 0;
#pragma unroll
  for (int d = 32; d > 0; d >>= 1) v += __shfl_down(v, d, 64);
  __shared__ int ws[4];
  if ((threadIdx.x & 63) == 0) ws[threadIdx.x >> 6] = v;
  __syncthreads();
  if (threadIdx.x == 0) bsum[blockIdx.y * NSCAN + blockIdx.x] = ws[0] + ws[1] + ws[2] + ws[3];
}

static __global__ void scanb_k(const int* __restrict__ bsum, int* __restrict__ bpre) {
  __shared__ int s[NSCAN];
  int base = blockIdx.x * NSCAN;
  int t = threadIdx.x;
  for (int i = t; i < NSCAN; i += blockDim.x) s[i] = bsum[base + i];
  __syncthreads();
  if (t == 0) {
    int run = 0;
    for (int i = 0; i < NSCAN; ++i) { int v = s[i]; s[i] = run; run += v; }
  }
  __syncthreads();
  for (int i = t; i < NSCAN; i += blockDim.x) bpre[base + i] = s[i];
}

static __global__ void rowptr_k(const int* __restrict__ degi, const int* __restrict__ degs,
                                const int* __restrict__ bpre,
                                int* __restrict__ rowptr, int* __restrict__ cursor,
                                int* __restrict__ rowptr2, int* __restrict__ cursor2) {
  const int* a = blockIdx.y ? degs : degi;
  int* rp = blockIdx.y ? rowptr2 : rowptr;
  int* cu = blockIdx.y ? cursor2 : cursor;
  int tid = threadIdx.x;
  int i = blockIdx.x * 256 + tid;
  int lane = tid & 63;
  int v = (i < N_NODES) ? a[i] : 0;
  int x = v;
#pragma unroll
  for (int d = 1; d < 64; d <<= 1) {
    int t = __shfl_up(x, d, 64);
    if (lane >= d) x += t;
  }
  __shared__ int wsum[4];
  if (lane == 63) wsum[tid >> 6] = x;
  __syncthreads();
  int add = bpre[blockIdx.y * NSCAN + blockIdx.x];
  for (int w = 0; w < (tid >> 6); ++w) add += wsum[w];
  int incl = x + add;
  if (i < N_NODES) {
    int excl = incl - v;
    rp[i] = excl;
    cu[i] = excl;
  }
  if (i == N_NODES - 1) rp[N_NODES] = incl;
}

// Fused CSR fill: dst-CSR col[] (src ids, for pull) AND src-CSR col2[]
// ((batch[dst], dinv[dst]) pairs, for push-pool). XCD-sliced cursors.
static __global__ void fillb_k(const int* __restrict__ ei, const int* __restrict__ batch,
                               const float* __restrict__ dinv,
                               int* __restrict__ cursor, int* __restrict__ col,
                               int* __restrict__ cursor2, int2* __restrict__ col2) {
  int slice = blockIdx.x & (XCD - 1);
  int lo = slice * SLICE_NODES;
  int hi = min(lo + SLICE_NODES, N_NODES);
  int bid = blockIdx.x >> 3;
  int stride = (gridDim.x >> 3) * blockDim.x;
  for (int e = bid * blockDim.x + threadIdx.x; e < N_EDGES; e += stride) {
    int s = ei[e];
    int d = ei[N_EDGES + e];
    if (d >= lo && d < hi) {
      int pos = atomicAdd(&cursor[d], 1);
      col[pos] = s;
    }
    if (s >= lo && s < hi) {
      int pos = atomicAdd(&cursor2[s], 1);
      col2[pos] = make_int2(batch[d], __float_as_int(dinv[d]));
    }
  }
}

// Layer-1 scalar aggregation -> packed pair (sagg, dinv) per node.
static __global__ void sagg_k(const int* __restrict__ rowptr, const int* __restrict__ col,
                              const float* __restrict__ xs, const float* __restrict__ dinv,
                              float2* __restrict__ pairs) {
  int n = blockIdx.x * blockDim.x + threadIdx.x;
  if (n >= N_NODES) return;
  float s = xs[n];
  int e0 = rowptr[n], e1 = rowptr[n + 1];
  int e = e0;
  for (; e + 4 <= e1; e += 4) {
    float v0 = xs[col[e]], v1 = xs[col[e + 1]], v2 = xs[col[e + 2]], v3 = xs[col[e + 3]];
    s += v0 + v1 + v2 + v3;
  }
  for (; e < e1; ++e) s += xs[col[e]];
  float di = dinv[n];
  pairs[n] = make_float2(s * di, di);
}

// Fused layer-1-materialize + layer-2-aggregate (8B/edge gather, L2-resident):
//   G[n,k] = dinv_n * sum_{i in {n} u N(n)} dinv_i * relu(sagg_i*W1_k + b1_k)
static __global__ __launch_bounds__(256) void l12_k(
    const int* __restrict__ rowptr, const int* __restrict__ col,
    const float2* __restrict__ pairs, const float* __restrict__ W1,
    const float* __restrict__ b1, float4* __restrict__ G4) {
  int node = blockIdx.x * 8 + (threadIdx.x >> 5);
  int q = threadIdx.x & 31;
  if (node >= N_NODES || q >= 25) return;
  float4 w = reinterpret_cast<const float4*>(W1)[q];
  float4 b = reinterpret_cast<const float4*>(b1)[q];
  float2 self = pairs[node];
  float4 acc;
  acc.x = self.y * fmaxf(fmaf(self.x, w.x, b.x), 0.0f);
  acc.y = self.y * fmaxf(fmaf(self.x, w.y, b.y), 0.0f);
  acc.z = self.y * fmaxf(fmaf(self.x, w.z, b.z), 0.0f);
  acc.w = self.y * fmaxf(fmaf(self.x, w.w, b.w), 0.0f);
  int e0 = rowptr[node], e1 = rowptr[node + 1];
  int e = e0;
#pragma unroll 1
  for (; e + 4 <= e1; e += 4) {
    float2 p0 = pairs[col[e]];
    float2 p1 = pairs[col[e + 1]];
    float2 p2 = pairs[col[e + 2]];
    float2 p3 = pairs[col[e + 3]];
    acc.x = fmaf(p0.y, fmaxf(fmaf(p0.x, w.x, b.x), 0.0f), acc.x);
    acc.y = fmaf(p0.y, fmaxf(fmaf(p0.x, w.y, b.y), 0.0f), acc.y);
    acc.z = fmaf(p0.y, fmaxf(fmaf(p0.x, w.z, b.z), 0.0f), acc.z);
    acc.w = fmaf(p0.y, fmaxf(fmaf(p0.x, w.w, b.w), 0.0f), acc.w);
    acc.x = fmaf(p1.y, fmaxf(fmaf(p1.x, w.x, b.x), 0.0f), acc.x);
    acc.y = fmaf(p1.y, fmaxf(fmaf(p1.x, w.y, b.y), 0.0f), acc.y);
    acc.z = fmaf(p1.y, fmaxf(fmaf(p1.x, w.z, b.z), 0.0f), acc.z);
    acc.w = fmaf(p1.y, fmaxf(fmaf(p1.x, w.w, b.w), 0.0f), acc.w);
    acc.x = fmaf(p2.y, fmaxf(fmaf(p2.x, w.x, b.x), 0.0f), acc.x);
    acc.y = fmaf(p2.y, fmaxf(fmaf(p2.x, w.y, b.y), 0.0f), acc.y);
    acc.z = fmaf(p2.y, fmaxf(fmaf(p2.x, w.z, b.z), 0.0f), acc.z);
    acc.w = fmaf(p2.y, fmaxf(fmaf(p2.x, w.w, b.w), 0.0f), acc.w);
    acc.x = fmaf(p3.y, fmaxf(fmaf(p3.x, w.x, b.x), 0.0f), acc.x);
    acc.y = fmaf(p3.y, fmaxf(fmaf(p3.x, w.y, b.y), 0.0f), acc.y);
    acc.z = fmaf(p3.y, fmaxf(fmaf(p3.x, w.z, b.z), 0.0f), acc.z);
    acc.w = fmaf(p3.y, fmaxf(fmaf(p3.x, w.w, b.w), 0.0f), acc.w);
  }
  for (; e < e1; ++e) {
    float2 p = pairs[col[e]];
    acc.x = fmaf(p.y, fmaxf(fmaf(p.x, w.x, b.x), 0.0f), acc.x);
    acc.y = fmaf(p.y, fmaxf(fmaf(p.x, w.y, b.y), 0.0f), acc.y);
    acc.z = fmaf(p.y, fmaxf(fmaf(p.x, w.z, b.z), 0.0f), acc.z);
    acc.w = fmaf(p.y, fmaxf(fmaf(p.x, w.w, b.w), 0.0f), acc.w);
  }
  float di = self.y;
  G4[node * 25 + q] = make_float4(acc.x * di, acc.y * di, acc.z * di, acc.w * di);
}

// Fused GEMM: hs2[n,:] = dinv[n] * relu(G[n,:] @ W + bias), stored FEATURE-
// PERMUTED: feature f = kc*25+k lands at word 4*k + kc. The push kernel's
// float4 at word 4q then holds features {q, q+25, q+50, q+75}, and its LDS
// adds land at slots {q, q+25, q+50, q+75} -> the accumulator ends up in
// NATURAL feature order (head2 indexes W3 directly).
// W via readfirstlane-forced scalar loads (SMEM pipe).
static __global__ __launch_bounds__(256) void gemm2_k(
    const float* __restrict__ G, const float* __restrict__ W,
    const float* __restrict__ bias, const float* __restrict__ dinv,
    float* __restrict__ Bout) {
  __shared__ float tile[64 * 101];
  const int nb = blockIdx.x * 64;
#pragma unroll
  for (int i = 0; i < 25; ++i) {
    int flat = i * 256 + threadIdx.x;          // 0..6399
    int n = flat / 100, j = flat - n * 100;
    float v = 0.0f;
    if (nb + n < N_NODES) v = G[(size_t)(nb + n) * 100 + j];
    tile[n * 101 + j] = v;
  }
  __syncthreads();
  const int lane = threadIdx.x & 63;
  const int kc = __builtin_amdgcn_readfirstlane(threadIdx.x >> 6);  // wave-uniform
  const int n = nb + lane;
  float acc[25];
#pragma unroll
  for (int k = 0; k < 25; ++k) acc[k] = 0.0f;
  const float* trow = &tile[lane * 101];
  const float* wbase = W + kc * 25;            // uniform pointer
#pragma unroll 4
  for (int j = 0; j < 100; ++j) {
    float wv[25];
    const float* wr = wbase + j * 100;         // uniform address -> s_load
#pragma unroll
    for (int k = 0; k < 25; ++k) wv[k] = wr[k];
    const float hj = trow[j];
#pragma unroll
    for (int k = 0; k < 25; ++k) acc[k] = fmaf(hj, wv[k], acc[k]);
  }
  if (n < N_NODES) {
    const float di = dinv[n];
    const int base = n * 100;
#pragma unroll
    for (int k = 0; k < 25; ++k) {
      float v = fmaxf(acc[k] + bias[kc * 25 + k], 0.0f) * di;
      Bout[base + 4 * k + kc] = v;   // permuted store: feature kc*25+k -> word 4k+kc
    }
  }
}

// Push-mode fused layer-3 aggregation + mean-pool numerators:
// stream each hs2 row once; add c*row into LDS pooled accumulator for the self
// term (c=dinv_i, g=batch[i]) and each out-edge (c=dinv_dst, g=batch[dst]).
// Lane q owns features {q,q+25,q+50,q+75}; adds land at those NATURAL slots
// (lane-consecutive addresses -> conflict-free). Per-block partials, reduced
// by redpart_k.
static __global__ __launch_bounds__(256) void push_k(
    const int* __restrict__ rowptr2, const int2* __restrict__ col2,
    const float4* __restrict__ B4, const int* __restrict__ batch,
    const float* __restrict__ dinv, float* __restrict__ partials) {
  __shared__ float pl[NG * HID];  // 51.2 KB
  for (int i = threadIdx.x; i < NG * HID; i += 256) pl[i] = 0.0f;
  __syncthreads();
  int grp = threadIdx.x >> 5;
  int q = threadIdx.x & 31;
  if (q < 25) {
    for (int oct = blockIdx.x; oct * 8 < N_NODES; oct += PUSH_BLOCKS) {
      int node = oct * 8 + grp;
      if (node >= N_NODES) continue;
      float4 r = B4[node * 25 + q];
      {  // self term
        float c = dinv[node];
        float* base = &pl[batch[node] * HID];
        atomicAdd(&base[q],      c * r.x);
        atomicAdd(&base[q + 25], c * r.y);
        atomicAdd(&base[q + 50], c * r.z);
        atomicAdd(&base[q + 75], c * r.w);
      }
      int e0 = rowptr2[node], e1 = rowptr2[node + 1];
      for (int e = e0; e < e1; ++e) {
        int2 tc = col2[e];
        float c = __int_as_float(tc.y);
        float* base = &pl[tc.x * HID];
        atomicAdd(&base[q],      c * r.x);
        atomicAdd(&base[q + 25], c * r.y);
        atomicAdd(&base[q + 50], c * r.z);
        atomicAdd(&base[q + 75], c * r.w);
      }
    }
  }
  __syncthreads();
  float* dst = partials + (size_t)blockIdx.x * (NG * HID);
  for (int i = threadIdx.x; i < NG * HID; i += 256) dst[i] = pl[i];
}

static __global__ void redpart_k(const float* __restrict__ partials,
                                 float* __restrict__ pooled) {
  int i = blockIdx.x * blockDim.x + threadIdx.x;
  if (i >= NG * HID) return;
  float s = 0.0f;
  for (int b = 0; b < PUSH_BLOCKS; ++b) s += partials[(size_t)b * (NG * HID) + i];
  pooled[i] = s;
}

static __device__ int lb(const int* __restrict__ a, int n, int v) {
  int lo = 0, hi = n;
  while (lo < hi) { int m = (lo + hi) >> 1; if (a[m] < v) lo = m + 1; else hi = m; }
  return lo;
}

// Head: counts via binary search on sorted batch; pooled is in NATURAL feature
// order (see push_k comment); t1 = mean @ W3 + b3; out = t1 @ Wl + bl.
static __global__ void head2_k(const float* __restrict__ pooled, const int* __restrict__ batch,
                               const float* __restrict__ W3, const float* __restrict__ b3,
                               const float* __restrict__ Wl, const float* __restrict__ bl,
                               float* __restrict__ out) {
  __shared__ float t1[HID];
  int g = blockIdx.x;
  int t = threadIdx.x;  // 128
  int lo = lb(batch, N_NODES, g);
  int hi = lb(batch, N_NODES, g + 1);
  float inv = 1.0f / fmaxf((float)(hi - lo), 1.0f);
  if (t < HID) {
    float acc = 0.0f;
#pragma unroll 4
    for (int j = 0; j < HID; ++j)
      acc = fmaf(pooled[g * HID + j] * inv, W3[j * HID + t], acc);
    t1[t] = acc + b3[t];
  }
  __syncthreads();
  if (t < NC) {
    float acc = 0.0f;
#pragma unroll 4
    for (int j = 0; j < HID; ++j)
      acc = fmaf(t1[j], Wl[j * NC + t], acc);
    out[g * NC + t] = acc + bl[t];
  }
}

extern "C" void kernel_launch(void* const* d_in, const int* in_sizes, int n_in,
                              void* d_out, int out_size, void* d_ws, size_t ws_size,
                              hipStream_t stream) {
  const float* x    = (const float*)d_in[0];
  const int* ei     = (const int*)d_in[1];   // [2, E] flattened: src then dst
  const int* batch  = (const int*)d_in[2];
  const float* W1   = (const float*)d_in[3];
  const float* b1   = (const float*)d_in[4];
  const float* W2   = (const float*)d_in[5];
  const float* b2   = (const float*)d_in[6];
  const float* W3   = (const float*)d_in[7];
  const float* b3   = (const float*)d_in[8];
  const float* Wl   = (const float*)d_in[9];
  const float* bl   = (const float*)d_in[10];
  float* out = (float*)d_out;

  char* p = (char*)d_ws;
  auto alloc = [&](size_t bytes) {
    char* q = p;
    p += (bytes + 255) & ~(size_t)255;
    return q;
  };
  int*   degi    = (int*)alloc((size_t)N_NODES * 2 * 4);  // degi | degs adjacent
  int*   degs    = degi + N_NODES;
  float* dinv    = (float*)alloc((size_t)N_NODES * 4);
  float* xs      = (float*)alloc((size_t)N_NODES * 4);
  float2* pairs  = (float2*)alloc((size_t)N_NODES * 8);
  int*   rowptr  = (int*)alloc((size_t)(N_NODES + 1) * 4);
  int*   rowptr2 = (int*)alloc((size_t)(N_NODES + 1) * 4);
  int*   cursor  = (int*)alloc((size_t)N_NODES * 4);
  int*   cursor2 = (int*)alloc((size_t)N_NODES * 4);
  int*   bsum    = (int*)alloc((size_t)NSCAN * 2 * 4);
  int*   bpre    = (int*)alloc((size_t)NSCAN * 2 * 4);
  int*   col     = (int*)alloc((size_t)N_EDGES * 4);
  int2*  col2    = (int2*)alloc((size_t)N_EDGES * 8);
  float* B       = (float*)alloc((size_t)N_NODES * HID * 4);  // hs2, permuted
  float* G       = (float*)alloc((size_t)N_NODES * HID * 4);  // layer-2 agg
  float* partials= (float*)alloc((size_t)PUSH_BLOCKS * NG * HID * 4);
  float* pooled  = (float*)alloc((size_t)NG * HID * 4);

  const int T = 256;
  int gN   = (N_NODES + T - 1) / T;
  int gAgg = (N_NODES + 7) / 8;
  int gGemm = (N_NODES + 63) / 64;

  (void)hipMemsetAsync(degi, 0, (size_t)N_NODES * 2 * 4, stream);
  degb_k<<<2048, T, 0, stream>>>(ei, degi, degs);
  dinv_k<<<gN, T, 0, stream>>>(degi, x, dinv, xs);
  reduce_k<<<dim3(NSCAN, 2), 256, 0, stream>>>(degi, degs, bsum);
  scanb_k<<<2, 256, 0, stream>>>(bsum, bpre);
  rowptr_k<<<dim3(NSCAN, 2), 256, 0, stream>>>(degi, degs, bpre, rowptr, cursor,
                                               rowptr2, cursor2);
  fillb_k<<<2048, T, 0, stream>>>(ei, batch, dinv, cursor, col, cursor2, col2);

  // layer 1: scalar aggregation -> (sagg, dinv) pairs
  sagg_k<<<gN, T, 0, stream>>>(rowptr, col, xs, dinv, pairs);

  // layer 2: fused layer-1-materialize + aggregate, then GEMM (permuted store)
  l12_k<<<gAgg, T, 0, stream>>>(rowptr, col, pairs, W1, b1, (float4*)G);
  gemm2_k<<<gGemm, T, 0, stream>>>(G, W2, b2, dinv, B);

  // layer 3 + pool: push-mode streamed aggregation into LDS accumulators
  push_k<<<PUSH_BLOCKS, T, 0, stream>>>(rowptr2, col2, (const float4*)B, batch,
                                        dinv, partials);
  redpart_k<<<(NG * HID + T - 1) / T, T, 0, stream>>>(partials, pooled);

  head2_k<<<NG, 128, 0, stream>>>(pooled, batch, W3, b3, Wl, bl, out);
}

// Round 11
// 1294.098 us; speedup vs baseline: 1.0285x; 1.0285x over previous
//
#include <hip/hip_runtime.h>

#define N_NODES 100000
#define N_EDGES 1600000
#define HID 100
#define NG 128
#define NC 8
#define NSCAN 391  // ceil(N_NODES / 256)
#define XCD 8
#define SLICE_NODES 12500  // N_NODES / XCD
#define PUSH_BLOCKS 512

// Degree count (in-deg AND out-deg), XCD-sliced: blocks with same blockIdx&7
// land on one XCD (perf heuristic); each slice-group streams src+dst coalesced
// and only atomics its own 12.5K-node window -> L2-local RMW.
static __global__ void degb_k(const int* __restrict__ ei, int* __restrict__ degi,
                              int* __restrict__ degs) {
  int slice = blockIdx.x & (XCD - 1);
  int lo = slice * SLICE_NODES;
  int hi = min(lo + SLICE_NODES, N_NODES);
  int bid = blockIdx.x >> 3;
  int stride = (gridDim.x >> 3) * blockDim.x;
  for (int e = bid * blockDim.x + threadIdx.x; e < N_EDGES; e += stride) {
    int s = ei[e];
    int d = ei[N_EDGES + e];
    if (d >= lo && d < hi) atomicAdd(&degi[d], 1);
    if (s >= lo && s < hi) atomicAdd(&degs[s], 1);
  }
}

// dinv (deg includes self-loop: 1+indeg) + xs = x*dinv.
static __global__ void dinv_k(const int* __restrict__ degi, const float* __restrict__ x,
                              float* __restrict__ dinv, float* __restrict__ xs) {
  int i = blockIdx.x * blockDim.x + threadIdx.x;
  if (i < N_NODES) {
    float d = 1.0f / sqrtf(1.0f + (float)degi[i]);
    dinv[i] = d;
    xs[i] = x[i] * d;
  }
}

// --- 3-phase parallel exclusive scan, two arrays via blockIdx.y (0:degi,1:degs) ---
static __global__ void reduce_k(const int* __restrict__ degi, const int* __restrict__ degs,
                                int* __restrict__ bsum) {
  const int* a = blockIdx.y ? degs : degi;
  int i = blockIdx.x * 256 + threadIdx.x;
  int v = (i < N_NODES) ? a[i] : 0;
#pragma unroll
  for (int d = 32; d > 0; d >>= 1) v += __shfl_down(v, d, 64);
  __shared__ int ws[4];
  if ((threadIdx.x & 63) == 0) ws[threadIdx.x >> 6] = v;
  __syncthreads();
  if (threadIdx.x == 0) bsum[blockIdx.y * NSCAN + blockIdx.x] = ws[0] + ws[1] + ws[2] + ws[3];
}

static __global__ void scanb_k(const int* __restrict__ bsum, int* __restrict__ bpre) {
  __shared__ int s[NSCAN];
  int base = blockIdx.x * NSCAN;
  int t = threadIdx.x;
  for (int i = t; i < NSCAN; i += blockDim.x) s[i] = bsum[base + i];
  __syncthreads();
  if (t == 0) {
    int run = 0;
    for (int i = 0; i < NSCAN; ++i) { int v = s[i]; s[i] = run; run += v; }
  }
  __syncthreads();
  for (int i = t; i < NSCAN; i += blockDim.x) bpre[base + i] = s[i];
}

static __global__ void rowptr_k(const int* __restrict__ degi, const int* __restrict__ degs,
                                const int* __restrict__ bpre,
                                int* __restrict__ rowptr, int* __restrict__ cursor,
                                int* __restrict__ rowptr2, int* __restrict__ cursor2) {
  const int* a = blockIdx.y ? degs : degi;
  int* rp = blockIdx.y ? rowptr2 : rowptr;
  int* cu = blockIdx.y ? cursor2 : cursor;
  int tid = threadIdx.x;
  int i = blockIdx.x * 256 + tid;
  int lane = tid & 63;
  int v = (i < N_NODES) ? a[i] : 0;
  int x = v;
#pragma unroll
  for (int d = 1; d < 64; d <<= 1) {
    int t = __shfl_up(x, d, 64);
    if (lane >= d) x += t;
  }
  __shared__ int wsum[4];
  if (lane == 63) wsum[tid >> 6] = x;
  __syncthreads();
  int add = bpre[blockIdx.y * NSCAN + blockIdx.x];
  for (int w = 0; w < (tid >> 6); ++w) add += wsum[w];
  int incl = x + add;
  if (i < N_NODES) {
    int excl = incl - v;
    rp[i] = excl;
    cu[i] = excl;
  }
  if (i == N_NODES - 1) rp[N_NODES] = incl;
}

// Fused CSR fill: dst-CSR col[] (src ids, pull) AND src-CSR col2[]
// ((batch[dst], dinv[dst]) pairs) + esrc[] (src id per src-CSR slot, for the
// edge-parallel push). XCD-sliced cursors.
static __global__ void fillb_k(const int* __restrict__ ei, const int* __restrict__ batch,
                               const float* __restrict__ dinv,
                               int* __restrict__ cursor, int* __restrict__ col,
                               int* __restrict__ cursor2, int2* __restrict__ col2,
                               int* __restrict__ esrc) {
  int slice = blockIdx.x & (XCD - 1);
  int lo = slice * SLICE_NODES;
  int hi = min(lo + SLICE_NODES, N_NODES);
  int bid = blockIdx.x >> 3;
  int stride = (gridDim.x >> 3) * blockDim.x;
  for (int e = bid * blockDim.x + threadIdx.x; e < N_EDGES; e += stride) {
    int s = ei[e];
    int d = ei[N_EDGES + e];
    if (d >= lo && d < hi) {
      int pos = atomicAdd(&cursor[d], 1);
      col[pos] = s;
    }
    if (s >= lo && s < hi) {
      int pos = atomicAdd(&cursor2[s], 1);
      col2[pos] = make_int2(batch[d], __float_as_int(dinv[d]));
      esrc[pos] = s;
    }
  }
}

// Layer-1 scalar aggregation -> packed pair (sagg, dinv) per node.
static __global__ void sagg_k(const int* __restrict__ rowptr, const int* __restrict__ col,
                              const float* __restrict__ xs, const float* __restrict__ dinv,
                              float2* __restrict__ pairs) {
  int n = blockIdx.x * blockDim.x + threadIdx.x;
  if (n >= N_NODES) return;
  float s = xs[n];
  int e0 = rowptr[n], e1 = rowptr[n + 1];
  int e = e0;
  for (; e + 4 <= e1; e += 4) {
    float v0 = xs[col[e]], v1 = xs[col[e + 1]], v2 = xs[col[e + 2]], v3 = xs[col[e + 3]];
    s += v0 + v1 + v2 + v3;
  }
  for (; e < e1; ++e) s += xs[col[e]];
  float di = dinv[n];
  pairs[n] = make_float2(s * di, di);
}

// Fused layer-1-materialize + layer-2-aggregate (8B/edge gather, L2-resident):
//   G[n,k] = dinv_n * sum_{i in {n} u N(n)} dinv_i * relu(sagg_i*W1_k + b1_k)
static __global__ __launch_bounds__(256) void l12_k(
    const int* __restrict__ rowptr, const int* __restrict__ col,
    const float2* __restrict__ pairs, const float* __restrict__ W1,
    const float* __restrict__ b1, float4* __restrict__ G4) {
  int node = blockIdx.x * 8 + (threadIdx.x >> 5);
  int q = threadIdx.x & 31;
  if (node >= N_NODES || q >= 25) return;
  float4 w = reinterpret_cast<const float4*>(W1)[q];
  float4 b = reinterpret_cast<const float4*>(b1)[q];
  float2 self = pairs[node];
  float4 acc;
  acc.x = self.y * fmaxf(fmaf(self.x, w.x, b.x), 0.0f);
  acc.y = self.y * fmaxf(fmaf(self.x, w.y, b.y), 0.0f);
  acc.z = self.y * fmaxf(fmaf(self.x, w.z, b.z), 0.0f);
  acc.w = self.y * fmaxf(fmaf(self.x, w.w, b.w), 0.0f);
  int e0 = rowptr[node], e1 = rowptr[node + 1];
  int e = e0;
#pragma unroll 1
  for (; e + 4 <= e1; e += 4) {
    float2 p0 = pairs[col[e]];
    float2 p1 = pairs[col[e + 1]];
    float2 p2 = pairs[col[e + 2]];
    float2 p3 = pairs[col[e + 3]];
    acc.x = fmaf(p0.y, fmaxf(fmaf(p0.x, w.x, b.x), 0.0f), acc.x);
    acc.y = fmaf(p0.y, fmaxf(fmaf(p0.x, w.y, b.y), 0.0f), acc.y);
    acc.z = fmaf(p0.y, fmaxf(fmaf(p0.x, w.z, b.z), 0.0f), acc.z);
    acc.w = fmaf(p0.y, fmaxf(fmaf(p0.x, w.w, b.w), 0.0f), acc.w);
    acc.x = fmaf(p1.y, fmaxf(fmaf(p1.x, w.x, b.x), 0.0f), acc.x);
    acc.y = fmaf(p1.y, fmaxf(fmaf(p1.x, w.y, b.y), 0.0f), acc.y);
    acc.z = fmaf(p1.y, fmaxf(fmaf(p1.x, w.z, b.z), 0.0f), acc.z);
    acc.w = fmaf(p1.y, fmaxf(fmaf(p1.x, w.w, b.w), 0.0f), acc.w);
    acc.x = fmaf(p2.y, fmaxf(fmaf(p2.x, w.x, b.x), 0.0f), acc.x);
    acc.y = fmaf(p2.y, fmaxf(fmaf(p2.x, w.y, b.y), 0.0f), acc.y);
    acc.z = fmaf(p2.y, fmaxf(fmaf(p2.x, w.z, b.z), 0.0f), acc.z);
    acc.w = fmaf(p2.y, fmaxf(fmaf(p2.x, w.w, b.w), 0.0f), acc.w);
    acc.x = fmaf(p3.y, fmaxf(fmaf(p3.x, w.x, b.x), 0.0f), acc.x);
    acc.y = fmaf(p3.y, fmaxf(fmaf(p3.x, w.y, b.y), 0.0f), acc.y);
    acc.z = fmaf(p3.y, fmaxf(fmaf(p3.x, w.z, b.z), 0.0f), acc.z);
    acc.w = fmaf(p3.y, fmaxf(fmaf(p3.x, w.w, b.w), 0.0f), acc.w);
  }
  for (; e < e1; ++e) {
    float2 p = pairs[col[e]];
    acc.x = fmaf(p.y, fmaxf(fmaf(p.x, w.x, b.x), 0.0f), acc.x);
    acc.y = fmaf(p.y, fmaxf(fmaf(p.x, w.y, b.y), 0.0f), acc.y);
    acc.z = fmaf(p.y, fmaxf(fmaf(p.x, w.z, b.z), 0.0f), acc.z);
    acc.w = fmaf(p.y, fmaxf(fmaf(p.x, w.w, b.w), 0.0f), acc.w);
  }
  float di = self.y;
  G4[node * 25 + q] = make_float4(acc.x * di, acc.y * di, acc.z * di, acc.w * di);
}

// Fused GEMM: hs2[n,:] = dinv[n] * relu(G[n,:] @ W + bias), NATURAL layout
// (contiguous per-lane 25-float runs -> dwordx4-mergeable stores).
// W via readfirstlane-forced scalar loads (SMEM pipe).
static __global__ __launch_bounds__(256) void gemm2_k(
    const float* __restrict__ G, const float* __restrict__ W,
    const float* __restrict__ bias, const float* __restrict__ dinv,
    float* __restrict__ Bout) {
  __shared__ float tile[64 * 101];
  const int nb = blockIdx.x * 64;
#pragma unroll
  for (int i = 0; i < 25; ++i) {
    int flat = i * 256 + threadIdx.x;          // 0..6399
    int n = flat / 100, j = flat - n * 100;
    float v = 0.0f;
    if (nb + n < N_NODES) v = G[(size_t)(nb + n) * 100 + j];
    tile[n * 101 + j] = v;
  }
  __syncthreads();
  const int lane = threadIdx.x & 63;
  const int kc = __builtin_amdgcn_readfirstlane(threadIdx.x >> 6);  // wave-uniform
  const int n = nb + lane;
  float acc[25];
#pragma unroll
  for (int k = 0; k < 25; ++k) acc[k] = 0.0f;
  const float* trow = &tile[lane * 101];
  const float* wbase = W + kc * 25;            // uniform pointer
#pragma unroll 4
  for (int j = 0; j < 100; ++j) {
    float wv[25];
    const float* wr = wbase + j * 100;         // uniform address -> s_load
#pragma unroll
    for (int k = 0; k < 25; ++k) wv[k] = wr[k];
    const float hj = trow[j];
#pragma unroll
    for (int k = 0; k < 25; ++k) acc[k] = fmaf(hj, wv[k], acc[k]);
  }
  if (n < N_NODES) {
    const float di = dinv[n];
    const int base = n * 100 + kc * 25;
#pragma unroll
    for (int k = 0; k < 25; ++k) {
      float v = fmaxf(acc[k] + bias[kc * 25 + k], 0.0f) * di;
      Bout[base + k] = v;
    }
  }
}

// Edge-parallel push-mode layer-3 + mean-pool numerators, feature-quartered:
// blockIdx.y = feature quarter (25 features, 12.8KB LDS accumulator -> 8
// blocks/CU). Grid-strides the src-sorted edge list: per edge, lane q does ONE
// 4B row load (L1-hot: ~16 consecutive edges share a src row) and ONE
// ds_add_f32 at pl[g*25+q] (lane-consecutive, conflict-free). 4-edge unroll
// for memory-level parallelism. Self terms handled the same way over nodes.
static __global__ __launch_bounds__(256) void push_k(
    const int2* __restrict__ col2, const int* __restrict__ esrc,
    const float* __restrict__ B, const int* __restrict__ batch,
    const float* __restrict__ dinv, float* __restrict__ partials) {
  __shared__ float pl[NG * 25];  // 12.8 KB
  for (int i = threadIdx.x; i < NG * 25; i += 256) pl[i] = 0.0f;
  __syncthreads();
  const int fbase = blockIdx.y * 25;
  const int grp = threadIdx.x >> 5;
  const int q = threadIdx.x & 31;
  if (q < 25) {
    const int nit = (N_EDGES + 32 * PUSH_BLOCKS - 1) / (32 * PUSH_BLOCKS);
    for (int it = 0; it < nit; ++it) {
      int ebase = (it * PUSH_BLOCKS + (int)blockIdx.x) * 32 + grp * 4;
      int2 tc[4]; int ss[4]; float v[4];
      int cnt = min(4, N_EDGES - ebase);
#pragma unroll
      for (int j = 0; j < 4; ++j)
        if (j < cnt) { tc[j] = col2[ebase + j]; ss[j] = esrc[ebase + j]; }
#pragma unroll
      for (int j = 0; j < 4; ++j)
        if (j < cnt) v[j] = B[ss[j] * 100 + fbase + q];
#pragma unroll
      for (int j = 0; j < 4; ++j)
        if (j < cnt) atomicAdd(&pl[tc[j].x * 25 + q], __int_as_float(tc[j].y) * v[j]);
    }
    const int nit2 = (N_NODES + 32 * PUSH_BLOCKS - 1) / (32 * PUSH_BLOCKS);
    for (int it = 0; it < nit2; ++it) {
      int nb = (it * PUSH_BLOCKS + (int)blockIdx.x) * 32 + grp * 4;
#pragma unroll
      for (int j = 0; j < 4; ++j) {
        int n = nb + j;
        if (n < N_NODES)
          atomicAdd(&pl[batch[n] * 25 + q], dinv[n] * B[n * 100 + fbase + q]);
      }
    }
  }
  __syncthreads();
  float* dst = partials + ((size_t)blockIdx.y * PUSH_BLOCKS + blockIdx.x) * (NG * 25);
  for (int i = threadIdx.x; i < NG * 25; i += 256) dst[i] = pl[i];
}

// Reduce per-block partials -> pooled[g*HID + f] (natural feature order).
static __global__ void redpart_k(const float* __restrict__ partials,
                                 float* __restrict__ pooled) {
  int i = blockIdx.x * blockDim.x + threadIdx.x;
  if (i >= NG * HID) return;
  int g = i / HID;
  int f = i - g * HID;
  int wq = f / 25;
  int q = f - wq * 25;
  const float* base = partials + (size_t)wq * PUSH_BLOCKS * (NG * 25) + g * 25 + q;
  float s = 0.0f;
  for (int b = 0; b < PUSH_BLOCKS; ++b) s += base[(size_t)b * (NG * 25)];
  pooled[i] = s;
}

static __device__ int lb(const int* __restrict__ a, int n, int v) {
  int lo = 0, hi = n;
  while (lo < hi) { int m = (lo + hi) >> 1; if (a[m] < v) lo = m + 1; else hi = m; }
  return lo;
}

// Head: counts via binary search on sorted batch; t1 = mean @ W3 + b3; out = t1 @ Wl + bl.
static __global__ void head2_k(const float* __restrict__ pooled, const int* __restrict__ batch,
                               const float* __restrict__ W3, const float* __restrict__ b3,
                               const float* __restrict__ Wl, const float* __restrict__ bl,
                               float* __restrict__ out) {
  __shared__ float t1[HID];
  int g = blockIdx.x;
  int t = threadIdx.x;  // 128
  int lo = lb(batch, N_NODES, g);
  int hi = lb(batch, N_NODES, g + 1);
  float inv = 1.0f / fmaxf((float)(hi - lo), 1.0f);
  if (t < HID) {
    float acc = 0.0f;
#pragma unroll 4
    for (int j = 0; j < HID; ++j)
      acc = fmaf(pooled[g * HID + j] * inv, W3[j * HID + t], acc);
    t1[t] = acc + b3[t];
  }
  __syncthreads();
  if (t < NC) {
    float acc = 0.0f;
#pragma unroll 4
    for (int j = 0; j < HID; ++j)
      acc = fmaf(t1[j], Wl[j * NC + t], acc);
    out[g * NC + t] = acc + bl[t];
  }
}

extern "C" void kernel_launch(void* const* d_in, const int* in_sizes, int n_in,
                              void* d_out, int out_size, void* d_ws, size_t ws_size,
                              hipStream_t stream) {
  const float* x    = (const float*)d_in[0];
  const int* ei     = (const int*)d_in[1];   // [2, E] flattened: src then dst
  const int* batch  = (const int*)d_in[2];
  const float* W1   = (const float*)d_in[3];
  const float* b1   = (const float*)d_in[4];
  const float* W2   = (const float*)d_in[5];
  const float* b2   = (const float*)d_in[6];
  const float* W3   = (const float*)d_in[7];
  const float* b3   = (const float*)d_in[8];
  const float* Wl   = (const float*)d_in[9];
  const float* bl   = (const float*)d_in[10];
  float* out = (float*)d_out;

  char* p = (char*)d_ws;
  auto alloc = [&](size_t bytes) {
    char* q = p;
    p += (bytes + 255) & ~(size_t)255;
    return q;
  };
  int*   degi    = (int*)alloc((size_t)N_NODES * 2 * 4);  // degi | degs adjacent
  int*   degs    = degi + N_NODES;
  float* dinv    = (float*)alloc((size_t)N_NODES * 4);
  float* xs      = (float*)alloc((size_t)N_NODES * 4);
  float2* pairs  = (float2*)alloc((size_t)N_NODES * 8);
  int*   rowptr  = (int*)alloc((size_t)(N_NODES + 1) * 4);
  int*   rowptr2 = (int*)alloc((size_t)(N_NODES + 1) * 4);
  int*   cursor  = (int*)alloc((size_t)N_NODES * 4);
  int*   cursor2 = (int*)alloc((size_t)N_NODES * 4);
  int*   bsum    = (int*)alloc((size_t)NSCAN * 2 * 4);
  int*   bpre    = (int*)alloc((size_t)NSCAN * 2 * 4);
  int*   col     = (int*)alloc((size_t)N_EDGES * 4);
  int2*  col2    = (int2*)alloc((size_t)N_EDGES * 8);
  int*   esrc    = (int*)alloc((size_t)N_EDGES * 4);
  float* B       = (float*)alloc((size_t)N_NODES * HID * 4);  // hs2, natural
  float* G       = (float*)alloc((size_t)N_NODES * HID * 4);  // layer-2 agg
  float* partials= (float*)alloc((size_t)4 * PUSH_BLOCKS * NG * 25 * 4);
  float* pooled  = (float*)alloc((size_t)NG * HID * 4);

  const int T = 256;
  int gN   = (N_NODES + T - 1) / T;
  int gAgg = (N_NODES + 7) / 8;
  int gGemm = (N_NODES + 63) / 64;

  (void)hipMemsetAsync(degi, 0, (size_t)N_NODES * 2 * 4, stream);
  degb_k<<<2048, T, 0, stream>>>(ei, degi, degs);
  dinv_k<<<gN, T, 0, stream>>>(degi, x, dinv, xs);
  reduce_k<<<dim3(NSCAN, 2), 256, 0, stream>>>(degi, degs, bsum);
  scanb_k<<<2, 256, 0, stream>>>(bsum, bpre);
  rowptr_k<<<dim3(NSCAN, 2), 256, 0, stream>>>(degi, degs, bpre, rowptr, cursor,
                                               rowptr2, cursor2);
  fillb_k<<<2048, T, 0, stream>>>(ei, batch, dinv, cursor, col, cursor2, col2, esrc);

  // layer 1: scalar aggregation -> (sagg, dinv) pairs
  sagg_k<<<gN, T, 0, stream>>>(rowptr, col, xs, dinv, pairs);

  // layer 2: fused layer-1-materialize + aggregate, then GEMM (natural store)
  l12_k<<<gAgg, T, 0, stream>>>(rowptr, col, pairs, W1, b1, (float4*)G);
  gemm2_k<<<gGemm, T, 0, stream>>>(G, W2, b2, dinv, B);

  // layer 3 + pool: edge-parallel feature-quartered push into LDS accumulators
  push_k<<<dim3(PUSH_BLOCKS, 4), T, 0, stream>>>(col2, esrc, B, batch, dinv, partials);
  redpart_k<<<(NG * HID + T - 1) / T, T, 0, stream>>>(partials, pooled);

  head2_k<<<NG, 128, 0, stream>>>(pooled, batch, W3, b3, Wl, bl, out);
}

// Round 12
// 441.942 us; speedup vs baseline: 3.0116x; 2.9282x over previous
//
#include <hip/hip_runtime.h>

#define N_NODES 100000
#define N_EDGES 1600000
#define HID 100
#define NG 128
#define NC 8
#define NSCAN 391  // ceil(N_NODES / 256)
#define XCD 8
#define SLICE_NODES 12500  // N_NODES / XCD

// degi[i]=1 accounts for the self-loop; zero pooled sums.
static __global__ void init_k(int* __restrict__ degi, float* __restrict__ pooled) {
  int i = blockIdx.x * blockDim.x + threadIdx.x;
  if (i < N_NODES) degi[i] = 1;
  if (i < NG * HID) pooled[i] = 0.0f;
}

// Degree count, XCD-sliced (blocks with same blockIdx&7 -> same XCD; perf
// heuristic only): stream dst coalesced, atomic only own 12.5K-node window.
static __global__ void deg_k(const int* __restrict__ ei, int* __restrict__ degi) {
  int slice = blockIdx.x & (XCD - 1);
  int lo = slice * SLICE_NODES;
  int hi = min(lo + SLICE_NODES, N_NODES);
  int bid = blockIdx.x >> 3;
  int stride = (gridDim.x >> 3) * blockDim.x;
  for (int e = bid * blockDim.x + threadIdx.x; e < N_EDGES; e += stride) {
    int d = ei[N_EDGES + e];
    if (d >= lo && d < hi) atomicAdd(&degi[d], 1);
  }
}

// dinv + pre-scaled node feature xs = x*dinv (layer-1 scalar message).
static __global__ void dinv_k(const int* __restrict__ degi, const float* __restrict__ x,
                              float* __restrict__ dinv, float* __restrict__ xs) {
  int i = blockIdx.x * blockDim.x + threadIdx.x;
  if (i < N_NODES) {
    float d = 1.0f / sqrtf((float)degi[i]);
    dinv[i] = d;
    xs[i] = x[i] * d;
  }
}

// --- 3-phase parallel exclusive scan of (degi-1) -> rowptr (+cursor copy) ---
static __global__ void reduce_k(const int* __restrict__ degi, int* __restrict__ bsum) {
  int i = blockIdx.x * 256 + threadIdx.x;
  int v = (i < N_NODES) ? degi[i] - 1 : 0;
#pragma unroll
  for (int d = 32; d > 0; d >>= 1) v += __shfl_down(v, d, 64);
  __shared__ int ws[4];
  if ((threadIdx.x & 63) == 0) ws[threadIdx.x >> 6] = v;
  __syncthreads();
  if (threadIdx.x == 0) bsum[blockIdx.x] = ws[0] + ws[1] + ws[2] + ws[3];
}

static __global__ void scanb_k(const int* __restrict__ bsum, int* __restrict__ bpre) {
  __shared__ int s[NSCAN];
  int t = threadIdx.x;
  for (int i = t; i < NSCAN; i += blockDim.x) s[i] = bsum[i];
  __syncthreads();
  if (t == 0) {
    int run = 0;
    for (int i = 0; i < NSCAN; ++i) { int v = s[i]; s[i] = run; run += v; }
  }
  __syncthreads();
  for (int i = t; i < NSCAN; i += blockDim.x) bpre[i] = s[i];
}

static __global__ void rowptr_k(const int* __restrict__ degi, const int* __restrict__ bpre,
                                int* __restrict__ rowptr, int* __restrict__ cursor) {
  int tid = threadIdx.x;
  int i = blockIdx.x * 256 + tid;
  int lane = tid & 63;
  int v = (i < N_NODES) ? degi[i] - 1 : 0;
  int x = v;
#pragma unroll
  for (int d = 1; d < 64; d <<= 1) {
    int t = __shfl_up(x, d, 64);
    if (lane >= d) x += t;
  }
  __shared__ int wsum[4];
  if (lane == 63) wsum[tid >> 6] = x;
  __syncthreads();
  int add = bpre[blockIdx.x];
  for (int w = 0; w < (tid >> 6); ++w) add += wsum[w];
  int incl = x + add;
  if (i < N_NODES) {
    int excl = incl - v;
    rowptr[i] = excl;
    cursor[i] = excl;  // fill cursor starts at row base
  }
  if (i == N_NODES - 1) rowptr[N_NODES] = incl;
}

// CSR fill, XCD-sliced: one atomic cursor bump per edge; col writes land in the
// slice's private ~800KB window (L2-local writebacks).
static __global__ void fill_k(const int* __restrict__ ei, int* __restrict__ cursor,
                              int* __restrict__ col) {
  int slice = blockIdx.x & (XCD - 1);
  int lo = slice * SLICE_NODES;
  int hi = min(lo + SLICE_NODES, N_NODES);
  int bid = blockIdx.x >> 3;
  int stride = (gridDim.x >> 3) * blockDim.x;
  for (int e = bid * blockDim.x + threadIdx.x; e < N_EDGES; e += stride) {
    int s = ei[e];             // unconditional: keep the src stream coalesced
    int d = ei[N_EDGES + e];
    if (d >= lo && d < hi) {
      int pos = atomicAdd(&cursor[d], 1);
      col[pos] = s;
    }
  }
}

// Layer-1 scalar aggregation -> packed pair (sagg, dinv) per node.
static __global__ void sagg_k(const int* __restrict__ rowptr, const int* __restrict__ col,
                              const float* __restrict__ xs, const float* __restrict__ dinv,
                              float2* __restrict__ pairs) {
  int n = blockIdx.x * blockDim.x + threadIdx.x;
  if (n >= N_NODES) return;
  float s = xs[n];
  int e0 = rowptr[n], e1 = rowptr[n + 1];
  int e = e0;
  for (; e + 4 <= e1; e += 4) {
    float v0 = xs[col[e]], v1 = xs[col[e + 1]], v2 = xs[col[e + 2]], v3 = xs[col[e + 3]];
    s += v0 + v1 + v2 + v3;
  }
  for (; e < e1; ++e) s += xs[col[e]];
  float di = dinv[n];
  pairs[n] = make_float2(s * di, di);
}

// Fused layer-1-materialize + layer-2-aggregate (8B/edge gather, L2-resident):
//   G[n,k] = dinv_n * sum_{i in {n} u N(n)} dinv_i * relu(sagg_i*W1_k + b1_k)
static __global__ __launch_bounds__(256) void l12_k(
    const int* __restrict__ rowptr, const int* __restrict__ col,
    const float2* __restrict__ pairs, const float* __restrict__ W1,
    const float* __restrict__ b1, float4* __restrict__ G4) {
  int node = blockIdx.x * 8 + (threadIdx.x >> 5);
  int q = threadIdx.x & 31;
  if (node >= N_NODES || q >= 25) return;
  float4 w = reinterpret_cast<const float4*>(W1)[q];
  float4 b = reinterpret_cast<const float4*>(b1)[q];
  float2 self = pairs[node];
  float4 acc;
  acc.x = self.y * fmaxf(fmaf(self.x, w.x, b.x), 0.0f);
  acc.y = self.y * fmaxf(fmaf(self.x, w.y, b.y), 0.0f);
  acc.z = self.y * fmaxf(fmaf(self.x, w.z, b.z), 0.0f);
  acc.w = self.y * fmaxf(fmaf(self.x, w.w, b.w), 0.0f);
  int e0 = rowptr[node], e1 = rowptr[node + 1];
  int e = e0;
#pragma unroll 1
  for (; e + 4 <= e1; e += 4) {
    float2 p0 = pairs[col[e]];
    float2 p1 = pairs[col[e + 1]];
    float2 p2 = pairs[col[e + 2]];
    float2 p3 = pairs[col[e + 3]];
    acc.x = fmaf(p0.y, fmaxf(fmaf(p0.x, w.x, b.x), 0.0f), acc.x);
    acc.y = fmaf(p0.y, fmaxf(fmaf(p0.x, w.y, b.y), 0.0f), acc.y);
    acc.z = fmaf(p0.y, fmaxf(fmaf(p0.x, w.z, b.z), 0.0f), acc.z);
    acc.w = fmaf(p0.y, fmaxf(fmaf(p0.x, w.w, b.w), 0.0f), acc.w);
    acc.x = fmaf(p1.y, fmaxf(fmaf(p1.x, w.x, b.x), 0.0f), acc.x);
    acc.y = fmaf(p1.y, fmaxf(fmaf(p1.x, w.y, b.y), 0.0f), acc.y);
    acc.z = fmaf(p1.y, fmaxf(fmaf(p1.x, w.z, b.z), 0.0f), acc.z);
    acc.w = fmaf(p1.y, fmaxf(fmaf(p1.x, w.w, b.w), 0.0f), acc.w);
    acc.x = fmaf(p2.y, fmaxf(fmaf(p2.x, w.x, b.x), 0.0f), acc.x);
    acc.y = fmaf(p2.y, fmaxf(fmaf(p2.x, w.y, b.y), 0.0f), acc.y);
    acc.z = fmaf(p2.y, fmaxf(fmaf(p2.x, w.z, b.z), 0.0f), acc.z);
    acc.w = fmaf(p2.y, fmaxf(fmaf(p2.x, w.w, b.w), 0.0f), acc.w);
    acc.x = fmaf(p3.y, fmaxf(fmaf(p3.x, w.x, b.x), 0.0f), acc.x);
    acc.y = fmaf(p3.y, fmaxf(fmaf(p3.x, w.y, b.y), 0.0f), acc.y);
    acc.z = fmaf(p3.y, fmaxf(fmaf(p3.x, w.z, b.z), 0.0f), acc.z);
    acc.w = fmaf(p3.y, fmaxf(fmaf(p3.x, w.w, b.w), 0.0f), acc.w);
  }
  for (; e < e1; ++e) {
    float2 p = pairs[col[e]];
    acc.x = fmaf(p.y, fmaxf(fmaf(p.x, w.x, b.x), 0.0f), acc.x);
    acc.y = fmaf(p.y, fmaxf(fmaf(p.x, w.y, b.y), 0.0f), acc.y);
    acc.z = fmaf(p.y, fmaxf(fmaf(p.x, w.z, b.z), 0.0f), acc.z);
    acc.w = fmaf(p.y, fmaxf(fmaf(p.x, w.w, b.w), 0.0f), acc.w);
  }
  float di = self.y;
  G4[node * 25 + q] = make_float4(acc.x * di, acc.y * di, acc.z * di, acc.w * di);
}

// Pull aggregation, float4 lanes: out[n,:] = dinv[n]*(B[n,:] + sum_{src->n} B[src,:]).
static __global__ __launch_bounds__(256) void agg4_k(
    const int* __restrict__ rowptr, const int* __restrict__ col,
    const float4* __restrict__ B4, const float* __restrict__ dinv,
    float4* __restrict__ out4) {
  int node = blockIdx.x * 8 + (threadIdx.x >> 5);
  int q = threadIdx.x & 31;
  if (node >= N_NODES || q >= 25) return;
  float4 acc = B4[node * 25 + q];  // self-loop
  int e0 = rowptr[node], e1 = rowptr[node + 1];
  int e = e0;
#pragma unroll 1
  for (; e + 4 <= e1; e += 4) {
    int s0 = col[e], s1 = col[e + 1], s2 = col[e + 2], s3 = col[e + 3];
    float4 v0 = B4[s0 * 25 + q];
    float4 v1 = B4[s1 * 25 + q];
    float4 v2 = B4[s2 * 25 + q];
    float4 v3 = B4[s3 * 25 + q];
    acc.x += v0.x + v1.x + v2.x + v3.x;
    acc.y += v0.y + v1.y + v2.y + v3.y;
    acc.z += v0.z + v1.z + v2.z + v3.z;
    acc.w += v0.w + v1.w + v2.w + v3.w;
  }
  for (; e < e1; ++e) {
    float4 v = B4[col[e] * 25 + q];
    acc.x += v.x; acc.y += v.y; acc.z += v.z; acc.w += v.w;
  }
  float di = dinv[node];
  out4[node * 25 + q] = make_float4(acc.x * di, acc.y * di, acc.z * di, acc.w * di);
}

// Fused GEMM: Bout[n,:] = dinv[n] * relu(G[n,:] @ W + bias).
// W forced to SCALAR loads (readfirstlane-uniform base -> s_load, SMEM pipe).
static __global__ __launch_bounds__(256) void gemm2_k(
    const float* __restrict__ G, const float* __restrict__ W,
    const float* __restrict__ bias, const float* __restrict__ dinv,
    float* __restrict__ Bout) {
  __shared__ float tile[64 * 101];
  const int nb = blockIdx.x * 64;
#pragma unroll
  for (int i = 0; i < 25; ++i) {
    int flat = i * 256 + threadIdx.x;          // 0..6399
    int n = flat / 100, j = flat - n * 100;
    float v = 0.0f;
    if (nb + n < N_NODES) v = G[(size_t)(nb + n) * 100 + j];
    tile[n * 101 + j] = v;
  }
  __syncthreads();
  const int lane = threadIdx.x & 63;
  const int kc = __builtin_amdgcn_readfirstlane(threadIdx.x >> 6);  // wave-uniform
  const int n = nb + lane;
  float acc[25];
#pragma unroll
  for (int k = 0; k < 25; ++k) acc[k] = 0.0f;
  const float* trow = &tile[lane * 101];
  const float* wbase = W + kc * 25;            // uniform pointer
#pragma unroll 4
  for (int j = 0; j < 100; ++j) {
    float wv[25];
    const float* wr = wbase + j * 100;         // uniform address -> s_load
#pragma unroll
    for (int k = 0; k < 25; ++k) wv[k] = wr[k];
    const float hj = trow[j];
#pragma unroll
    for (int k = 0; k < 25; ++k) acc[k] = fmaf(hj, wv[k], acc[k]);
  }
  if (n < N_NODES) {
    const float di = dinv[n];
    const int base = n * 100 + kc * 25;
#pragma unroll
    for (int k = 0; k < 25; ++k) {
      float v = fmaxf(acc[k] + bias[kc * 25 + k], 0.0f) * di;
      Bout[base + k] = v;
    }
  }
}

static __device__ int lb(const int* __restrict__ a, int n, int v) {
  int lo = 0, hi = n;
  while (lo < hi) { int m = (lo + hi) >> 1; if (a[m] < v) lo = m + 1; else hi = m; }
  return lo;
}

// Sorted-segment pool (sums + counts): 8 slices per graph, atomic per (g,slice,k).
#define PSLICES 8
static __global__ void pool2_k(const float* __restrict__ A, const int* __restrict__ batch,
                               float* __restrict__ pooled, float* __restrict__ counts) {
  int g = blockIdx.x;
  int slice = blockIdx.y;
  int k = threadIdx.x;  // 128 threads
  int lo = lb(batch, N_NODES, g);
  int hi = lb(batch, N_NODES, g + 1);
  int cnt = hi - lo;
  if (slice == 0 && k == 0) counts[g] = (float)cnt;
  int per = (cnt + PSLICES - 1) / PSLICES;
  int s0 = lo + slice * per;
  int s1 = min(s0 + per, hi);
  if (k < HID && s1 > s0) {
    float s = 0.0f;
    for (int n = s0; n < s1; ++n) s += A[n * HID + k];
    atomicAdd(&pooled[g * HID + k], s);
  }
}

// Head: t1 = mean_pooled @ W3 + b3 (per graph, in LDS), out = t1 @ Wl + bl.
static __global__ void head2_k(const float* __restrict__ pooled, const float* __restrict__ counts,
                               const float* __restrict__ W3, const float* __restrict__ b3,
                               const float* __restrict__ Wl, const float* __restrict__ bl,
                               float* __restrict__ out) {
  __shared__ float t1[HID];
  int g = blockIdx.x;
  int t = threadIdx.x;  // 128
  float inv = 1.0f / fmaxf(counts[g], 1.0f);
  if (t < HID) {
    float acc = 0.0f;
#pragma unroll 4
    for (int j = 0; j < HID; ++j)
      acc = fmaf(pooled[g * HID + j] * inv, W3[j * HID + t], acc);
    t1[t] = acc + b3[t];
  }
  __syncthreads();
  if (t < NC) {
    float acc = 0.0f;
#pragma unroll 4
    for (int j = 0; j < HID; ++j)
      acc = fmaf(t1[j], Wl[j * NC + t], acc);
    out[g * NC + t] = acc + bl[t];
  }
}

extern "C" void kernel_launch(void* const* d_in, const int* in_sizes, int n_in,
                              void* d_out, int out_size, void* d_ws, size_t ws_size,
                              hipStream_t stream) {
  const float* x    = (const float*)d_in[0];
  const int* ei     = (const int*)d_in[1];   // [2, E] flattened: src then dst
  const int* batch  = (const int*)d_in[2];
  const float* W1   = (const float*)d_in[3];
  const float* b1   = (const float*)d_in[4];
  const float* W2   = (const float*)d_in[5];
  const float* b2   = (const float*)d_in[6];
  const float* W3   = (const float*)d_in[7];
  const float* b3   = (const float*)d_in[8];
  const float* Wl   = (const float*)d_in[9];
  const float* bl   = (const float*)d_in[10];
  float* out = (float*)d_out;

  char* p = (char*)d_ws;
  auto alloc = [&](size_t bytes) {
    char* q = p;
    p += (bytes + 255) & ~(size_t)255;
    return q;
  };
  float* dinv   = (float*)alloc((size_t)N_NODES * 4);
  float* xs     = (float*)alloc((size_t)N_NODES * 4);
  float2* pairs = (float2*)alloc((size_t)N_NODES * 8);
  int*   degi   = (int*)alloc((size_t)N_NODES * 4);
  int*   rowptr = (int*)alloc((size_t)(N_NODES + 1) * 4);
  int*   cursor = (int*)alloc((size_t)N_NODES * 4);
  int*   bsum   = (int*)alloc((size_t)NSCAN * 4);
  int*   bpre   = (int*)alloc((size_t)NSCAN * 4);
  int*   col    = (int*)alloc((size_t)N_EDGES * 4);
  float* B      = (float*)alloc((size_t)N_NODES * HID * 4);  // hs2 (scaled H2)
  float* G      = (float*)alloc((size_t)N_NODES * HID * 4);  // layer-2 agg / M3
  float* pooled = (float*)alloc((size_t)NG * HID * 4);
  float* counts = (float*)alloc((size_t)NG * 4);

  const int T = 256;
  int gN   = (N_NODES + T - 1) / T;
  int gAgg = (N_NODES + 7) / 8;
  int gGemm = (N_NODES + 63) / 64;

  init_k<<<gN, T, 0, stream>>>(degi, pooled);
  deg_k<<<2048, T, 0, stream>>>(ei, degi);
  dinv_k<<<gN, T, 0, stream>>>(degi, x, dinv, xs);
  reduce_k<<<NSCAN, 256, 0, stream>>>(degi, bsum);
  scanb_k<<<1, 256, 0, stream>>>(bsum, bpre);
  rowptr_k<<<NSCAN, 256, 0, stream>>>(degi, bpre, rowptr, cursor);
  fill_k<<<2048, T, 0, stream>>>(ei, cursor, col);

  // layer 1: scalar aggregation -> (sagg, dinv) pairs
  sagg_k<<<gN, T, 0, stream>>>(rowptr, col, xs, dinv, pairs);

  // layer 2: fused layer-1-materialize + aggregate (8B/edge gather), then GEMM
  l12_k<<<gAgg, T, 0, stream>>>(rowptr, col, pairs, W1, b1, (float4*)G);
  gemm2_k<<<gGemm, T, 0, stream>>>(G, W2, b2, dinv, B);

  // layer 3: aggregate only (W3 commutes past the mean-pool)
  agg4_k<<<gAgg, T, 0, stream>>>(rowptr, col, (const float4*)B, dinv, (float4*)G);

  pool2_k<<<dim3(NG, PSLICES), 128, 0, stream>>>(G, batch, pooled, counts);
  head2_k<<<NG, 128, 0, stream>>>(pooled, counts, W3, b3, Wl, bl, out);
}